// Round 19
// baseline (110.834 us; speedup 1.0000x reference)
//
#include <hip/hip_runtime.h>
#include <hip/hip_bf16.h>
#include <stdint.h>

typedef __bf16 bf16x8 __attribute__((ext_vector_type(8)));
typedef float  f32x4  __attribute__((ext_vector_type(4)));
typedef unsigned short u16x8 __attribute__((ext_vector_type(8)));

#define NB 32
#define NC 128
#define NH 56
#define NW 56
#define NK 4
#define NCO 128
#define NCR 32
#define NHW 3136
#define TEMPER 30.0f

#define WS_ATTN   0u
#define WS_BC     4096u
#define WS_ROWSUM 65536u
#define WS_WC     1048576u
#define WS_XT     10485760u

__global__ void xt_kernel(const float* __restrict__ x, __hip_bfloat16* __restrict__ xt,
                          float* __restrict__ rowsum) {
  __shared__ float lds[58 * 133];
  int xcd = blockIdx.x & 7;
  int j   = blockIdx.x >> 3;
  int b   = xcd * 4 + j / 58;
  int hp  = j % 58;
  int blk = b * 58 + hp;
  int h = hp - 1;
  bool hin = (h >= 0) && (h < NH);
  int tid = threadIdx.x;
  if (hin) {
    const float* xrow = x + ((size_t)b * NC) * NHW + (size_t)h * NW;
    for (int i = tid; i < 128 * 14; i += 256) {
      int c = i / 14;
      int w4 = (i - c * 14) * 4;
      float4 v = *(const float4*)(xrow + (size_t)c * NHW + w4);
      int base = (w4 + 1) * 133 + c;
      lds[base]         = v.x;
      lds[base + 133]   = v.y;
      lds[base + 2*133] = v.z;
      lds[base + 3*133] = v.w;
    }
  }
  __syncthreads();
  __hip_bfloat16* orow = xt + (size_t)blk * (58 * 128);
  for (int i = tid; i < 58 * 16; i += 256) {
    int wp = i >> 4;
    int cg = (i & 15) << 3;
    u16x8 o;
    if (!hin || wp == 0 || wp == 57) {
      o = (u16x8)0;
    } else {
      const float* src = lds + wp * 133 + cg;
      #pragma unroll
      for (int jx = 0; jx < 8; ++jx) {
        union { __hip_bfloat16 b; unsigned short u; } cv;
        cv.b = __float2bfloat16(src[jx]);
        o[jx] = cv.u;
      }
    }
    *(u16x8*)(orow + wp * 128 + cg) = o;
  }
  if (hin && tid < 128) {
    float s = 0.f;
    #pragma unroll 8
    for (int wp = 1; wp <= 56; ++wp) s += lds[wp * 133 + tid];
    rowsum[(size_t)blk * 128 + tid] = s;
  }
}

__global__ void attn_kernel(const float* __restrict__ rowsum, const float* __restrict__ aw1,
                            const float* __restrict__ aw2, const float* __restrict__ bias,
                            float* __restrict__ attn, float* __restrict__ bc_out) {
  int b = blockIdx.x;
  __shared__ float sp[NC], h1[NCR], at[NK];
  int t = threadIdx.x;
  if (t < NC) {
    float s = 0.f;
    for (int hp = 1; hp <= 56; ++hp) s += rowsum[((size_t)b * 58 + hp) * 128 + t];
    sp[t] = s * (1.0f / (float)NHW);
  }
  __syncthreads();
  if (t < NCR) {
    float s = 0.f;
    for (int c = 0; c < NC; ++c) s += aw1[t*NC + c] * sp[c];
    h1[t] = s > 0.f ? s : 0.f;
  }
  __syncthreads();
  if (t == 0) {
    float lg[NK], mx = -1e30f;
    for (int k = 0; k < NK; ++k) {
      float s = 0.f;
      for (int r = 0; r < NCR; ++r) s += aw2[k*NCR + r] * h1[r];
      lg[k] = s * (1.0f/TEMPER);
      mx = fmaxf(mx, lg[k]);
    }
    float den = 0.f, e[NK];
    for (int k = 0; k < NK; ++k) { e[k] = expf(lg[k]-mx); den += e[k]; }
    float inv = 1.0f/den;
    for (int k = 0; k < NK; ++k) { at[k] = e[k]*inv; attn[b*NK+k] = at[k]; }
  }
  __syncthreads();
  if (t < NCO) {
    float s = 0.f;
    for (int k = 0; k < NK; ++k) s += at[k] * bias[k*NCO + t];
    bc_out[b*NCO + t] = s;
  }
}

__global__ void combine_kernel(const float* __restrict__ W, const float* __restrict__ attn,
                               __hip_bfloat16* __restrict__ wc) {
  int gid = blockIdx.x;
  int bg  = gid >> 6;
  int tcell = (gid & 63) * 256 + threadIdx.x;
  int co = tcell >> 7, ci = tcell & 127;
  float w[4][9];
  const float* wp = W + ((size_t)co * 128 + ci) * 9;
  #pragma unroll
  for (int k = 0; k < 4; ++k)
    #pragma unroll
    for (int j = 0; j < 9; ++j)
      w[k][j] = wp[(size_t)k * 147456 + j];
  for (int b = bg * 8; b < bg * 8 + 8; ++b) {
    float a0 = attn[b*4+0], a1 = attn[b*4+1], a2 = attn[b*4+2], a3 = attn[b*4+3];
    #pragma unroll
    for (int j = 0; j < 9; ++j) {
      float v = a0*w[0][j] + a1*w[1][j] + a2*w[2][j] + a3*w[3][j];
      wc[(((size_t)b*9 + j) * 128 + co) * 128 + ci] = __float2bfloat16(v);
    }
  }
}

// ------------------------------ conv ------------------------------
// WAVE-SPECIALIZED producer/consumer (the untried lever; AITER's approach).
// 10 waves: 8 CONSUMERS compute only (NEVER issue a global op -> their
// __syncthreads vmcnt(0) is a no-op; only lgkmcnt for their own ds_reads) --
// the drain-convoy that pinned R7-R17 at 40us cannot form. 2 PRODUCERS
// global_load_lds the NEXT step's A slab (and next-cc B tile) into double
// buffers; their per-step drain (~900cy) hides under consumer compute
// (~3300cy). ONE __syncthreads per step, 12 steps (4cc x 3kh).
// Consumers: wave = 64co x 112pos (mo=4, np=7), block output 128co x 448pos.
// Grid 224 (8 XCD x 28). LDS 147KB (A dbuf 2x24.6KB + B dbuf 2x49.2KB).
#define RS 2368            // B row stride in shorts (296 16B-slots, %8==0)
#define CS 40              // B col cell stride in shorts
#define ABUF 12288         // shorts: [3kwl][128co][32ci]
#define BBUF 24576         // shorts: 3072 chunks (2960 data + clamp pad)

#define GLOAD16(src, dst) \
  __builtin_amdgcn_global_load_lds( \
    (const __attribute__((address_space(1))) unsigned int*)(src), \
    (__attribute__((address_space(3))) unsigned int*)(dst), 16, 0, 0)

__global__ __launch_bounds__(640, 1) void conv_kernel(
    const unsigned short* __restrict__ xt,
    const unsigned short* __restrict__ wc,
    const float* __restrict__ bc,
    float* __restrict__ out) {
  __shared__ __align__(16) unsigned short lds_a[2*ABUF];   // 49,152 B
  __shared__ __align__(16) unsigned short lds_b[2*BBUF];   // 98,304 B
  const int tid  = threadIdx.x;        // 0..639 (10 waves)
  const int lane = tid & 63;
  const int wv   = tid >> 6;           // 0..7 consumers, 8..9 producers
  const int bid  = blockIdx.x;         // 224 = 8 xcd * 28
  const int xcd  = bid & 7;
  const int jj   = bid >> 3;
  const int b    = xcd*4 + jj/7;
  const int r0   = (jj % 7) * 8;       // 8 out rows per block
  const int li   = lane & 15;
  const int kg   = lane >> 4;

  const unsigned short* xtg = xt + (size_t)b*(58*58*128);
  const unsigned short* wcg = wc + (size_t)b*(9*128*128);

  // ---- producer maps (128 threads: ptid = tid - 512) ----
  const int ptid = tid - 512;
  const int pw   = wv - 8;             // producer wave 0..1
  // A: 1536 chunks -> 12 per producer thread; linear dest [kwl][co][32ci]
  int srcA[12];
  // B: 3072 chunks -> 24 per thread; clamped holes
  int srcB[24];
  if (tid >= 512) {
    #pragma unroll
    for (int i = 0; i < 12; ++i) {
      int c = i*128 + ptid;
      int kwl  = c >> 9;
      int co   = (c & 511) >> 2;
      int part = c & 3;
      srcA[i] = (kwl*128 + co)*128 + part*8;   // + kh*49152 + cc*32
    }
    #pragma unroll
    for (int i = 0; i < 24; ++i) {
      int q = i*128 + ptid;
      int r = q / 296;
      int sl = q - r*296;
      int col = sl / 5;
      int part = sl - col*5;
      int rc = r  > 9  ? 9  : r;
      int cl = col > 57 ? 57 : col;
      int pc = part > 3 ? 3 : part;
      srcB[i] = ((r0 + rc)*58 + cl)*128 + pc*8;
    }
  }

  // ---- consumer geometry ----
  const int wm = wv >> 2;              // 0..1 co strip *64 (consumers)
  const int wn = wv & 3;               // 0..3 pos strip *112
  int xoff[7];
  #pragma unroll
  for (int f = 0; f < 7; ++f) {
    int pos = wn*112 + f*16 + li;
    int rB = pos / 56;
    int cB = pos - rB*56;
    xoff[f] = rB*RS + cB*CS + kg*8;
  }
  const int aRead = (wm*64 + li)*32 + kg*8;

  const f32x4 vzero = {0.f, 0.f, 0.f, 0.f};
  f32x4 acc[4][7];
  #pragma unroll
  for (int mo = 0; mo < 4; ++mo)
    #pragma unroll
    for (int f = 0; f < 7; ++f) acc[mo][f] = vzero;

  #define STAGE_A(bufidx, ccn, khn) do { \
    unsigned short* dbase = lds_a + (bufidx)*ABUF + (pw*64)*8; \
    _Pragma("unroll") \
    for (int i = 0; i < 12; ++i) \
      GLOAD16(wcg + (khn)*49152 + srcA[i] + (ccn)*32, dbase + i*1024); \
  } while (0)

  #define STAGE_B(bufidx, ccn) do { \
    unsigned short* dbase = lds_b + (bufidx)*BBUF + (pw*64)*8; \
    _Pragma("unroll") \
    for (int i = 0; i < 24; ++i) \
      GLOAD16(xtg + srcB[i] + (ccn)*32, dbase + i*1024); \
  } while (0)

  #define COMPUTE(s, cc, kh) do { \
    const unsigned short* pa = lds_a + ((s)&1)*ABUF; \
    const unsigned short* pb = lds_b + ((cc)&1)*BBUF; \
    _Pragma("unroll") \
    for (int kwl = 0; kwl < 3; ++kwl) { \
      bf16x8 af[4], bf[7]; \
      _Pragma("unroll") \
      for (int mo = 0; mo < 4; ++mo) \
        af[mo] = *(const bf16x8*)(pa + kwl*4096 + aRead + mo*512); \
      _Pragma("unroll") \
      for (int f = 0; f < 7; ++f) \
        bf[f] = *(const bf16x8*)(pb + xoff[f] + (kh)*RS + kwl*CS); \
      __builtin_amdgcn_s_setprio(1); \
      _Pragma("unroll") \
      for (int mo = 0; mo < 4; ++mo) \
        _Pragma("unroll") \
        for (int f = 0; f < 7; ++f) \
          acc[mo][f] = __builtin_amdgcn_mfma_f32_16x16x32_bf16(af[mo], bf[f], acc[mo][f], 0, 0, 0); \
      __builtin_amdgcn_s_setprio(0); \
    } \
  } while (0)

  // STEP s: consumers compute buf[s]; producers stage buf[s+1] (A) and, at
  // kh==0, next-cc B. One __syncthreads ends the step: producer waves drain
  // their own gloads there (hidden under compute); consumer waves have no
  // outstanding vmem -> no drain.
  #define STEP(s, cc, kh) do { \
    if (tid >= 512) { \
      if ((s) < 11) STAGE_A(((s)+1)&1, ((s)+1)/3, ((s)+1)%3); \
      if ((kh) == 0 && (cc) < 3) STAGE_B(((cc)+1)&1, (cc)+1); \
    } else { \
      COMPUTE(s, cc, kh); \
    } \
    __syncthreads(); \
  } while (0)

  // prologue: producers stage step-0 buffers; consumers wait
  if (tid >= 512) {
    STAGE_A(0, 0, 0);
    STAGE_B(0, 0);
  }
  __syncthreads();

  STEP(0,  0, 0);
  STEP(1,  0, 1);
  STEP(2,  0, 2);
  STEP(3,  1, 0);
  STEP(4,  1, 1);
  STEP(5,  1, 2);
  STEP(6,  2, 0);
  STEP(7,  2, 1);
  STEP(8,  2, 2);
  STEP(9,  3, 0);
  STEP(10, 3, 1);
  STEP(11, 3, 2);

  if (tid < 512) {
    float* ob = out + (size_t)b*NCO*NHW;
    #pragma unroll
    for (int mo = 0; mo < 4; ++mo) {
      #pragma unroll
      for (int rg = 0; rg < 4; ++rg) {
        const int co = wm*64 + mo*16 + kg*4 + rg;
        const float bv = bc[b*NCO + co];
        float* orow = ob + (size_t)co*NHW;
        #pragma unroll
        for (int f = 0; f < 7; ++f) {
          int pos = wn*112 + f*16 + li;
          int rB = pos / 56;
          int cB = pos - rB*56;
          orow[(r0 + rB)*56 + cB] = acc[mo][f][rg] + bv;
        }
      }
    }
  }
}

extern "C" void kernel_launch(void* const* d_in, const int* in_sizes, int n_in,
                              void* d_out, int out_size, void* d_ws, size_t ws_size,
                              hipStream_t stream) {
  const float* x   = (const float*)d_in[0];
  const float* W   = (const float*)d_in[1];
  const float* bia = (const float*)d_in[2];
  const float* aw1 = (const float*)d_in[3];
  const float* aw2 = (const float*)d_in[4];
  float* out = (float*)d_out;
  char* ws = (char*)d_ws;
  float* attn   = (float*)(ws + WS_ATTN);
  float* bcm    = (float*)(ws + WS_BC);
  float* rowsum = (float*)(ws + WS_ROWSUM);
  __hip_bfloat16* wc = (__hip_bfloat16*)(ws + WS_WC);
  __hip_bfloat16* xt = (__hip_bfloat16*)(ws + WS_XT);

  xt_kernel<<<NB*58, 256, 0, stream>>>(x, xt, rowsum);
  attn_kernel<<<NB, 128, 0, stream>>>(rowsum, aw1, aw2, bia, attn, bcm);
  combine_kernel<<<256, 256, 0, stream>>>(W, attn, wc);
  conv_kernel<<<224, 640, 0, stream>>>((const unsigned short*)xt,
                                       (const unsigned short*)wc, bcm, out);
}

// Round 20
// 74.870 us; speedup vs baseline: 1.4804x; 1.4804x over previous
//
#include <hip/hip_runtime.h>
#include <hip/hip_bf16.h>
#include <stdint.h>

typedef __bf16 bf16x8 __attribute__((ext_vector_type(8)));
typedef float  f32x4  __attribute__((ext_vector_type(4)));
typedef unsigned short u16x8 __attribute__((ext_vector_type(8)));

#define NB 32
#define NC 128
#define NH 56
#define NW 56
#define NK 4
#define NCO 128
#define NCR 32
#define NHW 3136
#define TEMPER 30.0f

#define WS_ATTN   0u
#define WS_BC     4096u
#define WS_ROWSUM 65536u
#define WS_WC     1048576u
#define WS_XT     10485760u

__global__ void xt_kernel(const float* __restrict__ x, __hip_bfloat16* __restrict__ xt,
                          float* __restrict__ rowsum) {
  __shared__ float lds[58 * 133];
  int xcd = blockIdx.x & 7;
  int j   = blockIdx.x >> 3;
  int b   = xcd * 4 + j / 58;
  int hp  = j % 58;
  int blk = b * 58 + hp;
  int h = hp - 1;
  bool hin = (h >= 0) && (h < NH);
  int tid = threadIdx.x;
  if (hin) {
    const float* xrow = x + ((size_t)b * NC) * NHW + (size_t)h * NW;
    for (int i = tid; i < 128 * 14; i += 256) {
      int c = i / 14;
      int w4 = (i - c * 14) * 4;
      float4 v = *(const float4*)(xrow + (size_t)c * NHW + w4);
      int base = (w4 + 1) * 133 + c;
      lds[base]         = v.x;
      lds[base + 133]   = v.y;
      lds[base + 2*133] = v.z;
      lds[base + 3*133] = v.w;
    }
  }
  __syncthreads();
  __hip_bfloat16* orow = xt + (size_t)blk * (58 * 128);
  for (int i = tid; i < 58 * 16; i += 256) {
    int wp = i >> 4;
    int cg = (i & 15) << 3;
    u16x8 o;
    if (!hin || wp == 0 || wp == 57) {
      o = (u16x8)0;
    } else {
      const float* src = lds + wp * 133 + cg;
      #pragma unroll
      for (int jx = 0; jx < 8; ++jx) {
        union { __hip_bfloat16 b; unsigned short u; } cv;
        cv.b = __float2bfloat16(src[jx]);
        o[jx] = cv.u;
      }
    }
    *(u16x8*)(orow + wp * 128 + cg) = o;
  }
  if (hin && tid < 128) {
    float s = 0.f;
    #pragma unroll 8
    for (int wp = 1; wp <= 56; ++wp) s += lds[wp * 133 + tid];
    rowsum[(size_t)blk * 128 + tid] = s;
  }
}

__global__ void attn_kernel(const float* __restrict__ rowsum, const float* __restrict__ aw1,
                            const float* __restrict__ aw2, const float* __restrict__ bias,
                            float* __restrict__ attn, float* __restrict__ bc_out) {
  int b = blockIdx.x;
  __shared__ float sp[NC], h1[NCR], at[NK];
  int t = threadIdx.x;
  if (t < NC) {
    float s = 0.f;
    for (int hp = 1; hp <= 56; ++hp) s += rowsum[((size_t)b * 58 + hp) * 128 + t];
    sp[t] = s * (1.0f / (float)NHW);
  }
  __syncthreads();
  if (t < NCR) {
    float s = 0.f;
    for (int c = 0; c < NC; ++c) s += aw1[t*NC + c] * sp[c];
    h1[t] = s > 0.f ? s : 0.f;
  }
  __syncthreads();
  if (t == 0) {
    float lg[NK], mx = -1e30f;
    for (int k = 0; k < NK; ++k) {
      float s = 0.f;
      for (int r = 0; r < NCR; ++r) s += aw2[k*NCR + r] * h1[r];
      lg[k] = s * (1.0f/TEMPER);
      mx = fmaxf(mx, lg[k]);
    }
    float den = 0.f, e[NK];
    for (int k = 0; k < NK; ++k) { e[k] = expf(lg[k]-mx); den += e[k]; }
    float inv = 1.0f/den;
    for (int k = 0; k < NK; ++k) { at[k] = e[k]*inv; attn[b*NK+k] = at[k]; }
  }
  __syncthreads();
  if (t < NCO) {
    float s = 0.f;
    for (int k = 0; k < NK; ++k) s += at[k] * bias[k*NCO + t];
    bc_out[b*NCO + t] = s;
  }
}

__global__ void combine_kernel(const float* __restrict__ W, const float* __restrict__ attn,
                               __hip_bfloat16* __restrict__ wc) {
  int gid = blockIdx.x;
  int bg  = gid >> 6;
  int tcell = (gid & 63) * 256 + threadIdx.x;
  int co = tcell >> 7, ci = tcell & 127;
  float w[4][9];
  const float* wp = W + ((size_t)co * 128 + ci) * 9;
  #pragma unroll
  for (int k = 0; k < 4; ++k)
    #pragma unroll
    for (int j = 0; j < 9; ++j)
      w[k][j] = wp[(size_t)k * 147456 + j];
  for (int b = bg * 8; b < bg * 8 + 8; ++b) {
    float a0 = attn[b*4+0], a1 = attn[b*4+1], a2 = attn[b*4+2], a3 = attn[b*4+3];
    #pragma unroll
    for (int j = 0; j < 9; ++j) {
      float v = a0*w[0][j] + a1*w[1][j] + a2*w[2][j] + a3*w[3][j];
      wc[(((size_t)b*9 + j) * 128 + co) * 128 + ci] = __float2bfloat16(v);
    }
  }
}

// ------------------------------ conv ------------------------------
// A-IN-REGISTERS, B-only LDS. The cycle audit (R14 diags + per-SIMD math)
// showed A's LDS round-trip (write 294KB/block + read back) was ~60% of the
// LDS-pipe load and the super-additive term. A has only 4x in-wave reuse ->
// registers. R2's direct-L2 A failed because the compiler SANK the prefetch
// (VGPR 88-128 proof); here the 9 MFMA-groups/cc are fully unrolled with
// named E/O A-frag sets and sched_barrier(0) fences pinning
// [load A(g+1) -> ds_read B(g) -> MFMA(g)], so the compiler emits counted
// vmcnt(4) and A's ~400cy L2 latency hides under group-g's MFMA issue.
// LDS = 28.7KB (B only); barriers = 2/cc (8 total).
// Block 256 thr, 4 waves (2m x 2n), tile 128co x 224pos, grid 448 (XCD map).
// CHECK: VGPR_Count must read ~200-230 (<=128 means fences failed).
#define RS 2368            // B row stride in shorts (296 16B-slots, %8==0)
#define CS 40              // B col cell stride in shorts

#define GLOAD16(src, dst) \
  __builtin_amdgcn_global_load_lds( \
    (const __attribute__((address_space(1))) unsigned int*)(src), \
    (__attribute__((address_space(3))) unsigned int*)(dst), 16, 0, 0)

#define SB() __builtin_amdgcn_sched_barrier(0)

__global__ __launch_bounds__(256, 2) void conv_kernel(
    const unsigned short* __restrict__ xt,
    const unsigned short* __restrict__ wc,
    const float* __restrict__ bc,
    float* __restrict__ out) {
  __shared__ __align__(16) unsigned short lds_b[1792*8];   // 28,672 B (B only)
  const int tid  = threadIdx.x;
  const int lane = tid & 63;
  const int wv   = tid >> 6;
  const int wm   = wv & 1;             // co strip *64
  const int wn   = wv >> 1;            // pos strip *112
  const int bid  = blockIdx.x;         // 448 = 8 xcd * 56
  const int xcd  = bid & 7;
  const int jj   = bid >> 3;
  const int b    = xcd*4 + jj/14;
  const int r0   = (jj % 14) * 4;      // 4 out rows per block
  const int li   = lane & 15;
  const int kg   = lane >> 4;

  // B staging map: 6 rows x 296 slots = 1776 chunks; 7 iters x 256 (clamped)
  int srcB[7];
  #pragma unroll
  for (int i = 0; i < 7; ++i) {
    int q = i*256 + tid;
    int r = q / 296;
    int sl = q - r*296;
    int col = sl / 5;
    int part = sl - col*5;
    int rc = r > 5 ? 5 : r;
    int cl = col > 57 ? 57 : col;
    int pc = part > 3 ? 3 : part;
    srcB[i] = ((r0 + rc)*58 + cl)*128 + pc*8;
  }

  int xoff[7];
  #pragma unroll
  for (int f = 0; f < 7; ++f) {
    int pos = wn*112 + f*16 + li;
    int rB = pos / 56;
    int cB = pos - rB*56;
    xoff[f] = rB*RS + cB*CS + kg*8;
  }

  const f32x4 vzero = {0.f, 0.f, 0.f, 0.f};
  f32x4 acc[4][7];
  #pragma unroll
  for (int mo = 0; mo < 4; ++mo)
    #pragma unroll
    for (int f = 0; f < 7; ++f) acc[mo][f] = vzero;

  const unsigned short* xtg = xt + (size_t)b*(58*58*128);
  // per-lane A base: row = wm*64 + li (+mo*16), col = kg*8 (+cc*32)
  const unsigned short* wcA = wc + (size_t)b*(9*128*128) + (wm*64 + li)*128 + kg*8;

  #define LOADA(DST, khw, cc) do { \
    _Pragma("unroll") \
    for (int mo = 0; mo < 4; ++mo) \
      DST[mo] = *(const bf16x8*)(wcA + (khw)*16384 + mo*2048 + (cc)*32); \
  } while (0)

  // GROUP g: prefetch A(g+1) into NXT, read B(g), MFMA with CUR.
  #define GROUP(g, CUR, NXT, cc) do { \
    if ((g) < 8) { LOADA(NXT, (g)+1, cc); SB(); } \
    const int kh_ = (g)/3, kw_ = (g)-kh_*3; \
    const int koff_ = kh_*RS + kw_*CS; \
    bf16x8 bfr[7]; \
    _Pragma("unroll") \
    for (int f = 0; f < 7; ++f) \
      bfr[f] = *(const bf16x8*)(lds_b + xoff[f] + koff_); \
    SB(); \
    __builtin_amdgcn_s_setprio(1); \
    _Pragma("unroll") \
    for (int mo = 0; mo < 4; ++mo) \
      _Pragma("unroll") \
      for (int f = 0; f < 7; ++f) \
        acc[mo][f] = __builtin_amdgcn_mfma_f32_16x16x32_bf16(CUR[mo], bfr[f], acc[mo][f], 0, 0, 0); \
    __builtin_amdgcn_s_setprio(0); \
    SB(); \
  } while (0)

  for (int cc = 0; cc < 4; ++cc) {
    bf16x8 afE[4], afO[4];
    LOADA(afE, 0, cc);                 // group-0 A: FIFO head, regs only (safe pre-barrier)
    SB();
    __syncthreads();                   // prev-cc readers of lds_b done
    #pragma unroll
    for (int i = 0; i < 7; ++i)
      GLOAD16(xtg + srcB[i] + cc*32, lds_b + (i*256 + wv*64)*8);
    __syncthreads();                   // drain: B ready (afE also landed)

    GROUP(0, afE, afO, cc);
    GROUP(1, afO, afE, cc);
    GROUP(2, afE, afO, cc);
    GROUP(3, afO, afE, cc);
    GROUP(4, afE, afO, cc);
    GROUP(5, afO, afE, cc);
    GROUP(6, afE, afO, cc);
    GROUP(7, afO, afE, cc);
    GROUP(8, afE, afO, cc);
  }

  float* ob = out + (size_t)b*NCO*NHW;
  #pragma unroll
  for (int mo = 0; mo < 4; ++mo) {
    #pragma unroll
    for (int rg = 0; rg < 4; ++rg) {
      const int co = wm*64 + mo*16 + kg*4 + rg;
      const float bv = bc[b*NCO + co];
      float* orow = ob + (size_t)co*NHW;
      #pragma unroll
      for (int f = 0; f < 7; ++f) {
        int pos = wn*112 + f*16 + li;
        int rB = pos / 56;
        int cB = pos - rB*56;
        orow[(r0 + rB)*56 + cB] = acc[mo][f][rg] + bv;
      }
    }
  }
}

extern "C" void kernel_launch(void* const* d_in, const int* in_sizes, int n_in,
                              void* d_out, int out_size, void* d_ws, size_t ws_size,
                              hipStream_t stream) {
  const float* x   = (const float*)d_in[0];
  const float* W   = (const float*)d_in[1];
  const float* bia = (const float*)d_in[2];
  const float* aw1 = (const float*)d_in[3];
  const float* aw2 = (const float*)d_in[4];
  float* out = (float*)d_out;
  char* ws = (char*)d_ws;
  float* attn   = (float*)(ws + WS_ATTN);
  float* bcm    = (float*)(ws + WS_BC);
  float* rowsum = (float*)(ws + WS_ROWSUM);
  __hip_bfloat16* wc = (__hip_bfloat16*)(ws + WS_WC);
  __hip_bfloat16* xt = (__hip_bfloat16*)(ws + WS_XT);

  xt_kernel<<<NB*58, 256, 0, stream>>>(x, xt, rowsum);
  attn_kernel<<<NB, 128, 0, stream>>>(rowsum, aw1, aw2, bia, attn, bcm);
  combine_kernel<<<256, 256, 0, stream>>>(W, attn, wc);
  conv_kernel<<<448, 256, 0, stream>>>((const unsigned short*)xt,
                                       (const unsigned short*)wc, bcm, out);
}

// Round 21
// 66.729 us; speedup vs baseline: 1.6610x; 1.1220x over previous
//
#include <hip/hip_runtime.h>
#include <hip/hip_bf16.h>
#include <stdint.h>

typedef __bf16 bf16x8 __attribute__((ext_vector_type(8)));
typedef float  f32x4  __attribute__((ext_vector_type(4)));
typedef unsigned short u16x8 __attribute__((ext_vector_type(8)));

#define NB 32
#define NC 128
#define NH 56
#define NW 56
#define NK 4
#define NCO 128
#define NCR 32
#define NHW 3136
#define TEMPER 30.0f

#define WS_ATTN   0u
#define WS_BC     4096u
#define WS_ROWSUM 65536u
#define WS_WC     1048576u
#define WS_XT     10485760u

__global__ void xt_kernel(const float* __restrict__ x, __hip_bfloat16* __restrict__ xt,
                          float* __restrict__ rowsum) {
  __shared__ float lds[58 * 133];
  int xcd = blockIdx.x & 7;
  int j   = blockIdx.x >> 3;
  int b   = xcd * 4 + j / 58;
  int hp  = j % 58;
  int blk = b * 58 + hp;
  int h = hp - 1;
  bool hin = (h >= 0) && (h < NH);
  int tid = threadIdx.x;
  if (hin) {
    const float* xrow = x + ((size_t)b * NC) * NHW + (size_t)h * NW;
    for (int i = tid; i < 128 * 14; i += 256) {
      int c = i / 14;
      int w4 = (i - c * 14) * 4;
      float4 v = *(const float4*)(xrow + (size_t)c * NHW + w4);
      int base = (w4 + 1) * 133 + c;
      lds[base]         = v.x;
      lds[base + 133]   = v.y;
      lds[base + 2*133] = v.z;
      lds[base + 3*133] = v.w;
    }
  }
  __syncthreads();
  __hip_bfloat16* orow = xt + (size_t)blk * (58 * 128);
  for (int i = tid; i < 58 * 16; i += 256) {
    int wp = i >> 4;
    int cg = (i & 15) << 3;
    u16x8 o;
    if (!hin || wp == 0 || wp == 57) {
      o = (u16x8)0;
    } else {
      const float* src = lds + wp * 133 + cg;
      #pragma unroll
      for (int jx = 0; jx < 8; ++jx) {
        union { __hip_bfloat16 b; unsigned short u; } cv;
        cv.b = __float2bfloat16(src[jx]);
        o[jx] = cv.u;
      }
    }
    *(u16x8*)(orow + wp * 128 + cg) = o;
  }
  if (hin && tid < 128) {
    float s = 0.f;
    #pragma unroll 8
    for (int wp = 1; wp <= 56; ++wp) s += lds[wp * 133 + tid];
    rowsum[(size_t)blk * 128 + tid] = s;
  }
}

__global__ void attn_kernel(const float* __restrict__ rowsum, const float* __restrict__ aw1,
                            const float* __restrict__ aw2, const float* __restrict__ bias,
                            float* __restrict__ attn, float* __restrict__ bc_out) {
  int b = blockIdx.x;
  __shared__ float sp[NC], h1[NCR], at[NK];
  int t = threadIdx.x;
  if (t < NC) {
    float s = 0.f;
    for (int hp = 1; hp <= 56; ++hp) s += rowsum[((size_t)b * 58 + hp) * 128 + t];
    sp[t] = s * (1.0f / (float)NHW);
  }
  __syncthreads();
  if (t < NCR) {
    float s = 0.f;
    for (int c = 0; c < NC; ++c) s += aw1[t*NC + c] * sp[c];
    h1[t] = s > 0.f ? s : 0.f;
  }
  __syncthreads();
  if (t == 0) {
    float lg[NK], mx = -1e30f;
    for (int k = 0; k < NK; ++k) {
      float s = 0.f;
      for (int r = 0; r < NCR; ++r) s += aw2[k*NCR + r] * h1[r];
      lg[k] = s * (1.0f/TEMPER);
      mx = fmaxf(mx, lg[k]);
    }
    float den = 0.f, e[NK];
    for (int k = 0; k < NK; ++k) { e[k] = expf(lg[k]-mx); den += e[k]; }
    float inv = 1.0f/den;
    for (int k = 0; k < NK; ++k) { at[k] = e[k]*inv; attn[b*NK+k] = at[k]; }
  }
  __syncthreads();
  if (t < NCO) {
    float s = 0.f;
    for (int k = 0; k < NK; ++k) s += at[k] * bias[k*NCO + t];
    bc_out[b*NCO + t] = s;
  }
}

__global__ void combine_kernel(const float* __restrict__ W, const float* __restrict__ attn,
                               __hip_bfloat16* __restrict__ wc) {
  int gid = blockIdx.x;
  int bg  = gid >> 6;
  int tcell = (gid & 63) * 256 + threadIdx.x;
  int co = tcell >> 7, ci = tcell & 127;
  float w[4][9];
  const float* wp = W + ((size_t)co * 128 + ci) * 9;
  #pragma unroll
  for (int k = 0; k < 4; ++k)
    #pragma unroll
    for (int j = 0; j < 9; ++j)
      w[k][j] = wp[(size_t)k * 147456 + j];
  for (int b = bg * 8; b < bg * 8 + 8; ++b) {
    float a0 = attn[b*4+0], a1 = attn[b*4+1], a2 = attn[b*4+2], a3 = attn[b*4+3];
    #pragma unroll
    for (int j = 0; j < 9; ++j) {
      float v = a0*w[0][j] + a1*w[1][j] + a2*w[2][j] + a3*w[3][j];
      wc[(((size_t)b*9 + j) * 128 + co) * 128 + ci] = __float2bfloat16(v);
    }
  }
}

// ------------------------------ conv ------------------------------
// Locked-in best configuration (R13, measured 39.68us / 747 TF = 30% of
// dense peak -- at the measured grouped-GEMM 2-phase template band, m248).
// Serial-staged, phase-barrier pipelined compute; block = 128co x 224pos
// (4 out rows), 4 waves, grid 448 (XCD-aligned), 2 blocks/CU.
#define RS 2368            // B row stride in shorts (296 16B-slots, %8==0)
#define CS 40              // B col cell stride in shorts

#define GLOAD16(src, dst) \
  __builtin_amdgcn_global_load_lds( \
    (const __attribute__((address_space(1))) unsigned int*)(src), \
    (__attribute__((address_space(3))) unsigned int*)(dst), 16, 0, 0)

__global__ __launch_bounds__(256, 2) void conv_kernel(
    const unsigned short* __restrict__ xt,
    const unsigned short* __restrict__ wc,
    const float* __restrict__ bc,
    float* __restrict__ out) {
  __shared__ __align__(16) unsigned short lds_b[1792*8];   // 28,672 B
  __shared__ __align__(16) unsigned short lds_a[3*4096];   // 24,576 B [kwl][co][32ci]
  const int tid  = threadIdx.x;
  const int lane = tid & 63;
  const int wv   = tid >> 6;
  const int wm   = wv & 1;
  const int wn   = wv >> 1;
  const int bid  = blockIdx.x;         // 448 = 8 xcd * 56
  const int xcd  = bid & 7;
  const int jj   = bid >> 3;
  const int b    = xcd*4 + jj/14;
  const int r0   = (jj % 14) * 4;
  const int li   = lane & 15;
  const int kg   = lane >> 4;

  int srcB[7];
  #pragma unroll
  for (int i = 0; i < 7; ++i) {
    int q = i*256 + tid;
    int r = q / 296;
    int sl = q - r*296;
    int col = sl / 5;
    int part = sl - col*5;
    int rc = r > 5 ? 5 : r;
    int cl = col > 57 ? 57 : col;
    int pc = part > 3 ? 3 : part;
    srcB[i] = ((r0 + rc)*58 + cl)*128 + pc*8;
  }
  int srcA[6];
  #pragma unroll
  for (int i = 0; i < 6; ++i) {
    int c = i*256 + tid;
    int kwl  = c >> 9;
    int co   = (c & 511) >> 2;
    int part = c & 3;
    srcA[i] = (kwl*128 + co)*128 + part*8;   // + kh*49152 + cc*32 at stage
  }

  int xoff[7];
  #pragma unroll
  for (int f = 0; f < 7; ++f) {
    int pos = wn*112 + f*16 + li;
    int rB = pos / 56;
    int cB = pos - rB*56;
    xoff[f] = rB*RS + cB*CS + kg*8;
  }
  const int aRead = (wm*64 + li)*32 + kg*8;

  const f32x4 vzero = {0.f, 0.f, 0.f, 0.f};
  f32x4 acc[4][7];
  #pragma unroll
  for (int mo = 0; mo < 4; ++mo)
    #pragma unroll
    for (int f = 0; f < 7; ++f) acc[mo][f] = vzero;

  const unsigned short* xtg = xt + (size_t)b*(58*58*128);
  const unsigned short* wcg = wc + (size_t)b*(9*128*128);

  #define LOADFRAG(AF, BF, kwl, kh) do { \
    _Pragma("unroll") \
    for (int mo = 0; mo < 4; ++mo) \
      AF[mo] = *(const bf16x8*)(lds_a + (kwl)*4096 + aRead + mo*512); \
    _Pragma("unroll") \
    for (int f = 0; f < 7; ++f) \
      BF[f] = *(const bf16x8*)(lds_b + xoff[f] + (kh)*RS + (kwl)*CS); \
  } while (0)

  #define PRIO_MFMA(AF, BF) do { \
    __builtin_amdgcn_s_setprio(1); \
    _Pragma("unroll") \
    for (int mo = 0; mo < 4; ++mo) \
      _Pragma("unroll") \
      for (int f = 0; f < 7; ++f) \
        acc[mo][f] = __builtin_amdgcn_mfma_f32_16x16x32_bf16(AF[mo], BF[f], acc[mo][f], 0, 0, 0); \
    __builtin_amdgcn_s_setprio(0); \
  } while (0)

  for (int cc = 0; cc < 4; ++cc) {
    #pragma unroll
    for (int kh = 0; kh < 3; ++kh) {
      __syncthreads();                 // readers of lds_a/lds_b done
      #pragma unroll
      for (int i = 0; i < 6; ++i)
        GLOAD16(wcg + kh*49152 + srcA[i] + cc*32, lds_a + (i*256 + wv*64)*8);
      if (kh == 0) {
        #pragma unroll
        for (int i = 0; i < 7; ++i)
          GLOAD16(xtg + srcB[i] + cc*32, lds_b + (i*256 + wv*64)*8);
      }
      __syncthreads();                 // staged data ready

      bf16x8 afE[4], bfE[7], afO[4], bfO[7];
      LOADFRAG(afE, bfE, 0, kh);
      __builtin_amdgcn_s_barrier();
      LOADFRAG(afO, bfO, 1, kh);
      PRIO_MFMA(afE, bfE);
      __builtin_amdgcn_s_barrier();
      LOADFRAG(afE, bfE, 2, kh);
      PRIO_MFMA(afO, bfO);
      __builtin_amdgcn_s_barrier();
      PRIO_MFMA(afE, bfE);
    }
  }

  float* ob = out + (size_t)b*NCO*NHW;
  #pragma unroll
  for (int mo = 0; mo < 4; ++mo) {
    #pragma unroll
    for (int rg = 0; rg < 4; ++rg) {
      const int co = wm*64 + mo*16 + kg*4 + rg;
      const float bv = bc[b*NCO + co];
      float* orow = ob + (size_t)co*NHW;
      #pragma unroll
      for (int f = 0; f < 7; ++f) {
        int pos = wn*112 + f*16 + li;
        int rB = pos / 56;
        int cB = pos - rB*56;
        orow[(r0 + rB)*56 + cB] = acc[mo][f][rg] + bv;
      }
    }
  }
}

extern "C" void kernel_launch(void* const* d_in, const int* in_sizes, int n_in,
                              void* d_out, int out_size, void* d_ws, size_t ws_size,
                              hipStream_t stream) {
  const float* x   = (const float*)d_in[0];
  const float* W   = (const float*)d_in[1];
  const float* bia = (const float*)d_in[2];
  const float* aw1 = (const float*)d_in[3];
  const float* aw2 = (const float*)d_in[4];
  float* out = (float*)d_out;
  char* ws = (char*)d_ws;
  float* attn   = (float*)(ws + WS_ATTN);
  float* bcm    = (float*)(ws + WS_BC);
  float* rowsum = (float*)(ws + WS_ROWSUM);
  __hip_bfloat16* wc = (__hip_bfloat16*)(ws + WS_WC);
  __hip_bfloat16* xt = (__hip_bfloat16*)(ws + WS_XT);

  xt_kernel<<<NB*58, 256, 0, stream>>>(x, xt, rowsum);
  attn_kernel<<<NB, 128, 0, stream>>>(rowsum, aw1, aw2, bia, attn, bcm);
  combine_kernel<<<256, 256, 0, stream>>>(W, attn, wc);
  conv_kernel<<<448, 256, 0, stream>>>((const unsigned short*)xt,
                                       (const unsigned short*)wc, bcm, out);
}